// Round 3
// baseline (468.306 us; speedup 1.0000x reference)
//
#include <hip/hip_runtime.h>
#include <math.h>

#define KK 15
#define K1 16
#define NN 4096
#define BSZ 128
#define NT 512
#define RPT 8          // rows per thread = NN/NT
#define NPAIR 4        // packed row pairs per thread
#define NW 8           // waves per block
#define EPSI 0.1f
#define SMALLC 1e-20f
#define NITER 200
#define W2STRIDE 65536
#define OUT_A_ELEMS (BSZ * NN * KK)
#define TS 20          // wbufT row stride in floats (16B-aligned, 2-way-conflict-free)

typedef __attribute__((ext_vector_type(2))) float f2;
__device__ __forceinline__ f2 pk_fma(f2 a, f2 b, f2 c){
  return __builtin_elementwise_fma(a, b, c);
}

// ---------- sortable float <-> uint encoding for atomic min/max ----------
__device__ __forceinline__ unsigned enc_f32(float f){
  unsigned u = __float_as_uint(f);
  return (u & 0x80000000u) ? ~u : (u | 0x80000000u);
}
__device__ __forceinline__ float dec_f32(unsigned e){
  unsigned u = (e & 0x80000000u) ? (e ^ 0x80000000u) : ~e;
  return __uint_as_float(u);
}

// ws layout (uint32): [0]=max_enc(0) [1]=neg_flag(0) [2]=norm^2 accum f32(0)
//                     [3]=arrive ctr(0) [4]=done ctr(0) [5]=min_enc(0xFFFFFFFF)

// ---------- 16-column lane-fold reduction ----------
__device__ __forceinline__ int fold_col(int lane){
  int l = lane & 15;
  return ((l & 1) << 3) | ((l & 2) << 1) | ((l & 4) >> 1) | ((l & 8) >> 3);
}

__device__ __forceinline__ float wave_fold16(const float p[K1], int lane){
  float a[8];
  {
    const bool hi = (lane & 1) != 0;
    #pragma unroll
    for (int j = 0; j < 8; ++j){
      float send = hi ? p[j] : p[j + 8];
      float keep = hi ? p[j + 8] : p[j];
      a[j] = keep + __shfl_xor(send, 1);
    }
  }
  float bq[4];
  {
    const bool hi = (lane & 2) != 0;
    #pragma unroll
    for (int j = 0; j < 4; ++j){
      float send = hi ? a[j] : a[j + 4];
      float keep = hi ? a[j + 4] : a[j];
      bq[j] = keep + __shfl_xor(send, 2);
    }
  }
  float cq[2];
  {
    const bool hi = (lane & 4) != 0;
    float s0 = hi ? bq[0] : bq[2];
    float s1 = hi ? bq[1] : bq[3];
    float k0 = hi ? bq[2] : bq[0];
    float k1 = hi ? bq[3] : bq[1];
    cq[0] = k0 + __shfl_xor(s0, 4);
    cq[1] = k1 + __shfl_xor(s1, 4);
  }
  float r;
  {
    const bool hi = (lane & 8) != 0;
    float send = hi ? cq[0] : cq[1];
    float keep = hi ? cq[1] : cq[0];
    r = keep + __shfl_xor(send, 8);
  }
  r += __shfl_xor(r, 16);
  r += __shfl_xor(r, 32);
  return r;
}

__device__ __forceinline__ void block_fold16(const float p[K1], float* wb, float* tb,
                                             int lane, int wv, int tid){
  float r = wave_fold16(p, lane);
  if (lane < 16) wb[wv * K1 + fold_col(lane)] = r;
  __syncthreads();
  if (tid < 16){
    float t = 0.0f;
    #pragma unroll
    for (int q = 0; q < NW; ++q) t += wb[q * K1 + tid];
    tb[tid] = t;
  }
  __syncthreads();
}

__global__ __launch_bounds__(NT, 2) void k_main(
    const float* __restrict__ scores, const float* __restrict__ taup,
    const float* __restrict__ w1, const float* __restrict__ w2,
    float* __restrict__ out, unsigned* __restrict__ ws){
  const int b = blockIdx.x;
  const int tid = threadIdx.x;
  const int lane = tid & 63;
  const int wv = tid >> 6;

  __shared__ float scratch[NN];
  __shared__ float tk[KK];
  __shared__ __align__(16) float cbuf[K1];
  __shared__ float wbuf[NW * K1];
  __shared__ __align__(16) float xbuf[K1];
  __shared__ __align__(16) float wbufT[2][K1 * TS];
  __shared__ __align__(16) float wvt[NW * K1];
  __shared__ float rv[NW];
  __shared__ int ri[NW];
  __shared__ float rmn[NW];
  __shared__ unsigned sng[NW];
  __shared__ float statb[4];

  // ---- load raw row ----
  float raw[RPT];
  #pragma unroll
  for (int j = 0; j < RPT; ++j) raw[j] = scores[(size_t)b * NN + tid + NT * j];

  // ---- fused global min/max/neg (was k_minmax): local reduce + atomics + spin ----
  {
    float mx = -INFINITY, mn = INFINITY; unsigned neg = 0u;
    #pragma unroll
    for (int j = 0; j < RPT; ++j){
      float v = raw[j];
      mx = fmaxf(mx, v);
      if (v == -INFINITY) neg = 1u; else mn = fminf(mn, v);
    }
    #pragma unroll
    for (int off = 32; off; off >>= 1){
      mx = fmaxf(mx, __shfl_xor(mx, off));
      mn = fminf(mn, __shfl_xor(mn, off));
      neg |= (unsigned)__shfl_xor((int)neg, off);
    }
    if (lane == 0){ rv[wv] = mx; rmn[wv] = mn; sng[wv] = neg; }
    __syncthreads();
    if (tid == 0){
      for (int q = 1; q < NW; ++q){
        mx = fmaxf(mx, rv[q]); mn = fminf(mn, rmn[q]); neg |= sng[q];
      }
      atomicMax(&ws[0], enc_f32(mx));
      atomicMin(&ws[5], enc_f32(mn));
      if (neg) atomicOr(&ws[1], 1u);
      __threadfence();
      atomicAdd(&ws[3], 1u);
      while (__hip_atomic_load(&ws[3], __ATOMIC_ACQUIRE, __HIP_MEMORY_SCOPE_AGENT) < (unsigned)BSZ)
        __builtin_amdgcn_s_sleep(2);
      statb[0] = dec_f32(__hip_atomic_load(&ws[0], __ATOMIC_RELAXED, __HIP_MEMORY_SCOPE_AGENT));
      statb[1] = dec_f32(__hip_atomic_load(&ws[5], __ATOMIC_RELAXED, __HIP_MEMORY_SCOPE_AGENT));
      statb[2] = __hip_atomic_load(&ws[1], __ATOMIC_RELAXED, __HIP_MEMORY_SCOPE_AGENT) ? 1.0f : 0.0f;
    }
    __syncthreads();
  }

  const float smax = statb[0];
  const float smin_raw = statb[1];
  const bool has_neg = statb[2] != 0.0f;
  const float filled = smin_raw - (smax - smin_raw);
  const float smin_eff = has_neg ? filled : smin_raw;
  const float cmax = fmaxf(fmaxf(smin_eff * smin_eff, smax * smax),
                           fmaxf((smin_eff - 15.0f) * (smin_eff - 15.0f),
                                 (smax - 15.0f) * (smax - 15.0f)));
  const float cinv = 1.0f / cmax;
  const float tauv = taup[0];
  const float inv_n = 1.0f / (float)NN;   // 2^-12, exact

  // ---- fixed s values in regs; scratch for top-k ----
  float sfix[RPT];
  #pragma unroll
  for (int j = 0; j < RPT; ++j){
    float v = raw[j];
    if (v == -INFINITY) v = filled;
    sfix[j] = v;
    scratch[tid + NT * j] = v;
  }
  __syncthreads();

  // ---- top-15 by iterative argmax ----
  for (int t = 0; t < KK; ++t){
    float bv = -INFINITY; int bi = NN;
    #pragma unroll
    for (int j = 0; j < RPT; ++j){
      int i = tid + NT * j;
      float v = scratch[i];
      if (v > bv){ bv = v; bi = i; }
    }
    #pragma unroll
    for (int off = 32; off; off >>= 1){
      float ov = __shfl_xor(bv, off);
      int oi = __shfl_xor(bi, off);
      if (ov > bv || (ov == bv && oi < bi)){ bv = ov; bi = oi; }
    }
    if (lane == 0){ rv[wv] = bv; ri[wv] = bi; }
    __syncthreads();
    if (tid == 0){
      for (int q = 1; q < NW; ++q){
        if (rv[q] > bv || (rv[q] == bv && ri[q] < bi)){ bv = rv[q]; bi = ri[q]; }
      }
      tk[t] = bv;
      scratch[bi] = -INFINITY;
    }
    __syncthreads();
  }

  // ---- Gamma0 column sums ----
  {
    float p[K1];
    float tkr[KK];
    #pragma unroll
    for (int c = 0; c < KK; ++c) tkr[c] = tk[c];
    #pragma unroll
    for (int c = 0; c < K1; ++c) p[c] = 0.0f;
    for (int j = 0; j < RPT; ++j){
      float si = sfix[j];
      #pragma unroll
      for (int c = 0; c < KK; ++c){
        float z = fabsf(tkr[c] - si) / tauv;
        float raw1 = 1.0f / (1.0f + expf(z)) + SMALLC;
        p[c] += raw1;
      }
    }
    block_fold16(p, wbuf, cbuf, lane, wv, tid);
  }

  // ---- warm start x_r = <b, weight2[r,:]> ----
  {
    float p[K1];
    float tkr[KK], colr[KK];
    #pragma unroll
    for (int c = 0; c < KK; ++c){ tkr[c] = tk[c]; colr[c] = cbuf[c]; }
    #pragma unroll
    for (int c = 0; c < K1; ++c) p[c] = 0.0f;
    for (int j = 0; j < RPT; ++j){
      int i = tid + NT * j;
      float si = sfix[j];
      float bb[K1];
      float rowpart = 0.0f;
      #pragma unroll
      for (int c = 0; c < KK; ++c){
        float d = si - (float)(KK - c);
        float Cc = d * d * cinv;
        float z = fabsf(tkr[c] - si) / tauv;
        float raw1 = 1.0f / (1.0f + expf(z)) + SMALLC;
        float g0 = (raw1 / colr[c]) * inv_n;
        rowpart += g0;
        bb[c] = Cc + EPSI * logf(g0);
      }
      {
        float Cc = si * si * cinv;  // anchor 0 for c=15
        float g0l = fminf(fmaxf(inv_n - rowpart, SMALLC), 1.0f - SMALLC);
        bb[KK] = Cc + EPSI * logf(g0l);
      }
      #pragma unroll
      for (int r = 0; r < 5; ++r){
        const float4* wp = (const float4*)(w2 + (size_t)r * W2STRIDE + (size_t)i * K1);
        float4 a0 = wp[0], a1 = wp[1], a2 = wp[2], a3 = wp[3];
        float acc = p[r];
        acc += bb[0] * a0.x + bb[1] * a0.y + bb[2] * a0.z + bb[3] * a0.w;
        acc += bb[4] * a1.x + bb[5] * a1.y + bb[6] * a1.z + bb[7] * a1.w;
        acc += bb[8] * a2.x + bb[9] * a2.y + bb[10] * a2.z + bb[11] * a2.w;
        acc += bb[12] * a3.x + bb[13] * a3.y + bb[14] * a3.z + bb[15] * a3.w;
        p[r] = acc;
      }
    }
    block_fold16(p, wbuf, xbuf, lane, wv, tid);
  }

  // ---- vt init: vt_c = B_c * exp(g_c/eps); vt[15] = 1 ----
  float vt[K1];
  {
    float xv[5];
    #pragma unroll
    for (int r = 0; r < 5; ++r) xv[r] = xbuf[r];
    #pragma unroll
    for (int c = 0; c < KK; ++c){
      float g = 0.0f;
      #pragma unroll
      for (int r = 0; r < 5; ++r) g += xv[r] * w1[(size_t)(NN + c) * 5 + r];
      vt[c] = expf(g * 10.0f);
    }
    vt[KK] = 1.0f;
  }

  // ---- E in registers, packed over row pairs: E2[q][c] = {E(row 2q), E(row 2q+1)} ----
  f2 E2[NPAIR][K1];
  #pragma unroll
  for (int q = 0; q < NPAIR; ++q){
    float s0 = sfix[2 * q], s1 = sfix[2 * q + 1];
    #pragma unroll
    for (int c = 0; c < K1; ++c){
      float a = (float)(KK - c);
      float d0 = s0 - a, d1 = s1 - a;
      f2 e;
      e.x = expf(d0 * d0 * (-10.0f * cinv));
      e.y = expf(d1 * d1 * (-10.0f * cinv));
      E2[q][c] = e;
    }
  }

  // ---- 200 Sinkhorn iterations (scaling form).
  // Per iter: H_j = sum_c E_jc vt_c ; t_j = rcp(H_j) (inv_n deferred);
  // p_c = sum_j E_jc t_j ; vt_c = nmul_c * rcp(block_total(p_c)).
  // One barrier/iter: fold -> wbufT[parity] -> barrier -> every wave
  // redundantly sums the 8 wave-partials (bitwise identical) + rebroadcast.
  f2 t2[NPAIR];
  const float nmul = ((lane & 15) < KK) ? 1.0f : 4081.0f;  // nu_c * NN
  #pragma unroll 1
  for (int it = 0; it < NITER; ++it){
    #pragma unroll
    for (int q = 0; q < NPAIR; ++q){
      f2 v0; v0.x = vt[0]; v0.y = vt[0];
      f2 h = E2[q][0] * v0;
      #pragma unroll
      for (int c = 1; c < K1; ++c){
        f2 vc; vc.x = vt[c]; vc.y = vt[c];
        h = pk_fma(E2[q][c], vc, h);
      }
      f2 t; t.x = __builtin_amdgcn_rcpf(h.x); t.y = __builtin_amdgcn_rcpf(h.y);
      t2[q] = t;
    }
    float p[K1];
    #pragma unroll
    for (int c = 0; c < K1; ++c){
      f2 acc = E2[0][c] * t2[0];
      acc = pk_fma(E2[1][c], t2[1], acc);
      acc = pk_fma(E2[2][c], t2[2], acc);
      acc = pk_fma(E2[3][c], t2[3], acc);
      p[c] = acc.x + acc.y;
    }
    float r = wave_fold16(p, lane);
    if (lane < 16) wbufT[it & 1][fold_col(lane) * TS + wv] = r;
    __syncthreads();
    {
      const float* wp = &wbufT[it & 1][(lane & 15) * TS];
      float4 a4 = *(const float4*)wp;
      float4 b4 = *(const float4*)(wp + 4);
      float t = ((a4.x + a4.y) + (a4.z + a4.w)) + ((b4.x + b4.y) + (b4.z + b4.w));
      float nv = nmul * __builtin_amdgcn_rcpf(t);
      if (lane < 16) wvt[wv * K1 + (lane & 15)] = nv;
      // same-wave LDS write->read: compiler inserts lgkmcnt wait; no barrier.
      float4 v0 = *(const float4*)&wvt[wv * K1 + 0];
      float4 v1 = *(const float4*)&wvt[wv * K1 + 4];
      float4 v2 = *(const float4*)&wvt[wv * K1 + 8];
      float4 v3 = *(const float4*)&wvt[wv * K1 + 12];
      vt[0] = v0.x; vt[1] = v0.y; vt[2] = v0.z; vt[3] = v0.w;
      vt[4] = v1.x; vt[5] = v1.y; vt[6] = v1.z; vt[7] = v1.w;
      vt[8] = v2.x; vt[9] = v2.y; vt[10] = v2.z; vt[11] = v2.w;
      vt[12] = v3.x; vt[13] = v3.y; vt[14] = v3.z; vt[15] = v3.w;
    }
  }

  // ---- epilogue: Gamma = E * (inv_n*t) * vt; A = Gamma[:,:,:15]*n; norm^2 ----
  float nrm = 0.0f;
  {
    float tkr[KK], colr[KK];
    #pragma unroll
    for (int c = 0; c < KK; ++c){ tkr[c] = tk[c]; colr[c] = cbuf[c]; }
    for (int j = 0; j < RPT; ++j){
      int i = tid + NT * j;
      float si = sfix[j];
      f2 tq = t2[j >> 1];
      float tt = ((j & 1) ? tq.y : tq.x) * inv_n;
      float rowpart = 0.0f;
      float* op = out + (size_t)(b * NN + i) * KK;
      #pragma unroll
      for (int c = 0; c < KK; ++c){
        f2 e = E2[j >> 1][c];
        float Ev = (j & 1) ? e.y : e.x;
        float gam = Ev * tt * vt[c];
        float z = fabsf(tkr[c] - si) / tauv;
        float raw1 = 1.0f / (1.0f + expf(z)) + SMALLC;
        float g0 = (raw1 / colr[c]) * inv_n;
        rowpart += g0;
        float d = gam - g0;
        nrm += d * d;
        op[c] = gam * (float)NN;
      }
      {
        f2 e = E2[j >> 1][KK];
        float Ev = (j & 1) ? e.y : e.x;
        float gam = Ev * tt * vt[KK];
        float g0l = fminf(fmaxf(inv_n - rowpart, SMALLC), 1.0f - SMALLC);
        float d = gam - g0l;
        nrm += d * d;
      }
    }
  }
  #pragma unroll
  for (int off = 32; off; off >>= 1) nrm += __shfl_xor(nrm, off);
  if (lane == 0) rv[wv] = nrm;
  __syncthreads();
  if (tid == 0){
    float t = 0.0f;
    for (int q = 0; q < NW; ++q) t += rv[q];
    atomicAdd(reinterpret_cast<float*>(ws) + 2, t);
    __threadfence();
    unsigned prev = atomicAdd(&ws[4], 1u);
    if (prev == (unsigned)(BSZ - 1)){
      float n2 = __hip_atomic_load(reinterpret_cast<float*>(ws) + 2,
                                   __ATOMIC_RELAXED, __HIP_MEMORY_SCOPE_AGENT);
      out[OUT_A_ELEMS] = sqrtf(n2);
    }
  }
}

extern "C" void kernel_launch(void* const* d_in, const int* in_sizes, int n_in,
                              void* d_out, int out_size, void* d_ws, size_t ws_size,
                              hipStream_t stream){
  const float* scores = (const float*)d_in[0];
  const float* tau    = (const float*)d_in[1];
  const float* w1     = (const float*)d_in[2];  // (4111, 5) row-major
  const float* w2     = (const float*)d_in[3];  // (5, 65536) row-major
  float* out = (float*)d_out;
  unsigned* ws = (unsigned*)d_ws;

  // [0]=max_enc 0, [1]=neg 0, [2]=norm 0.f, [3]=arrive 0, [4]=done 0, [5]=min_enc FF
  hipMemsetAsync(ws, 0x00, 20, stream);
  hipMemsetAsync((char*)ws + 20, 0xFF, 4, stream);

  k_main<<<BSZ, NT, 0, stream>>>(scores, tau, w1, w2, out, ws);
}